// Round 14
// baseline (465.326 us; speedup 1.0000x reference)
//
#include <hip/hip_runtime.h>

typedef unsigned short u16;
typedef unsigned int u32;

using short8 = __attribute__((ext_vector_type(8))) short;
using f32x4  = __attribute__((ext_vector_type(4))) float;
using float4v = __attribute__((ext_vector_type(4))) float;

#define LOG2E 1.44269504088896340736f

// X1 row (per batch): [h1 0:128 | pad] (u16)
#define X1S 136
// H2 row: [h2 0:64 | pad]
#define H2S 72
#define DBS 40
// XCH row stride: 8 steps * 40 + 8 pad
#define XCS 328

__device__ __forceinline__ u16 f2bf(float f) {
  u32 u = __float_as_uint(f);
  return (u16)((u + 0x7FFFu + ((u >> 16) & 1u)) >> 16);
}
__device__ __forceinline__ float sigm(float x) {
  return __builtin_amdgcn_rcpf(1.0f + __builtin_amdgcn_exp2f(-LOG2E * x));
}
__device__ __forceinline__ float tanh_(float x) {
  return 1.0f - 2.0f * __builtin_amdgcn_rcpf(1.0f + __builtin_amdgcn_exp2f(2.0f * LOG2E * x));
}
__device__ __forceinline__ f32x4 mfma_(short8 a, short8 b, f32x4 c) {
  return __builtin_amdgcn_mfma_f32_16x16x32_bf16(a, b, c, 0, 0, 0);
}

// R14 = R13 numerics/structure at 768 threads (12 waves, 3/SIMD):
//   waves 0-7:  L1 only (16 units each: 20 MFMA + 4 elem rows)
//   waves 8-11: L2 (16 units each: 24 MFMA + 4 rows) + x-chunk loader + head
// Per-SIMD work unchanged (64 MFMA) but 3 waves of TLP cover each other's
// MFMA-drain / LDS-latency / transcendental chains.
__global__ __launch_bounds__(768, 1) void spc_lstm(
    const float* __restrict__ xh,   const float* __restrict__ xfr,
    const float* __restrict__ Wih1, const float* __restrict__ Whh1,
    const float* __restrict__ bih1, const float* __restrict__ bhh1,
    const float* __restrict__ Wih2, const float* __restrict__ Whh2,
    const float* __restrict__ bih2, const float* __restrict__ bhh2,
    const float* __restrict__ Wd,   const float* __restrict__ bd,
    const float* __restrict__ Wf,   const float* __restrict__ bfv,
    const float* __restrict__ ob,   float* __restrict__ out)
{
  __shared__ __align__(16) u16 X1[2][16 * X1S];   //  8704 B
  __shared__ __align__(16) u16 H2B[2][16 * H2S];  //  4608 B
  __shared__ __align__(16) u16 DB[16 * DBS];      //  1280 B
  __shared__ __align__(16) u16 W1xF[32 * 512];    // 32768 B (zeros k>=16 baked)
  __shared__ __align__(16) u16 W2F[64 * 512];     // 65536 B
  __shared__ __align__(16) u16 WdF[4 * 512];      //  4096 B
  __shared__ __align__(16) u16 WfF[512];          //  1024 B
  __shared__ __align__(16) u16 XCH[2][16 * XCS];  // 20992 B x chunk ring
  // total ~135.8 KB

  const int tid = threadIdx.x;
  const int wv  = tid >> 6;          // 0..11
  const int l   = tid & 63;
  const int c   = l & 15;
  const int q   = l >> 4;
  const int bb  = blockIdx.x << 4;
  const bool isL1 = (wv < 8);        // waves 0-7: L1; waves 8-11: L2 + chunks + head
  const int w2  = wv - 8;            // L2 wave id 0..3

  // overlaid weights: L1 waves use [ty][0..3] = Whh1 (64 VGPR);
  // L2 waves use [ty][0..1] = Whh2 (32 VGPR)
  short8 wreg[4][4];
  float  br[4];

  // ---- zero activation + chunk LDS ----
  for (int i = tid; i < 2 * 16 * X1S; i += 768) ((u16*)X1)[i] = 0;
  for (int i = tid; i < 2 * 16 * H2S; i += 768) ((u16*)H2B)[i] = 0;
  for (int i = tid; i < 16 * DBS; i += 768) DB[i] = 0;
  for (int i = tid; i < 2 * 16 * XCS; i += 768) ((u16*)XCH)[i] = 0;
  __syncthreads();

  // ---- weight LDS fills (fragment-linear: (k,n) -> ((k>>3)*16+n)*8 + (k&7)) ----
  for (int i = tid; i < 64 * 512; i += 768) {         // Wih2 tiles (ww, ty, kc)
    const int rid = i >> 9, e = i & 511, k = e >> 4, n = e & 15;
    const int ww = rid >> 4, ty = (rid >> 2) & 3, kc = rid & 3;
    const int g = ty * 64 + ww * 16 + n;
    W2F[rid * 512 + ((k >> 3) * 16 + n) * 8 + (k & 7)] = f2bf(Wih2[g * 128 + kc * 32 + k]);
  }
  for (int i = tid; i < 32 * 512; i += 768) {         // Wih1 x-frags FULL (zeros k>=16)
    const int T = i >> 9, e = i & 511, k = e >> 4, n = e & 15;
    const int ty = T >> 3, uv = T & 7;
    const int g = ty * 128 + uv * 16 + n;
    W1xF[T * 512 + ((k >> 3) * 16 + n) * 8 + (k & 7)] =
        (k < 16) ? f2bf(Wih1[g * 16 + k]) : (u16)0;
  }
  for (int i = tid; i < 4 * 512; i += 768) {          // Wd tiles (ww, kc2)
    const int tix = i >> 9, e = i & 511, k = e >> 4, n = e & 15;
    const int ww = tix >> 1, kc2 = tix & 1;
    WdF[tix * 512 + ((k >> 3) * 16 + n) * 8 + (k & 7)] =
        f2bf(Wd[(ww * 16 + n) * 64 + kc2 * 32 + k]);
  }
  {                                                   // Wf (zeros n>=2)
    const int k = tid >> 4, n = tid & 15;
    if (tid < 512)
      WfF[((k >> 3) * 16 + n) * 8 + (k & 7)] = (n < 2) ? f2bf(Wf[n * 32 + k]) : (u16)0;
  }

  // ---- chunk 0 load (L2 waves): steps 0-7 into XCH[0] ----
  if (!isL1) {
    const int i0 = tid - 512;
    #pragma unroll
    for (int p = 0; p < 2; p++) {
      const int idx = i0 + p * 256;
      const int r = idx >> 5, rem = idx & 31, st = rem >> 2, hf = rem & 3;
      const float4v v = *(const float4v*)&xh[(bb + r) * 3200 + st * 16 + hf * 4];
      u16* d = &XCH[0][r * XCS + st * 40 + hf * 4];
      d[0] = f2bf(v[0]); d[1] = f2bf(v[1]); d[2] = f2bf(v[2]); d[3] = f2bf(v[3]);
    }
  }

  // ---- register weights / biases ----
  if (isL1) {
    #pragma unroll
    for (int ty = 0; ty < 4; ty++) {
      const int g = ty * 128 + wv * 16 + c;
      br[ty] = bih1[g] + bhh1[g];
      #pragma unroll
      for (int kc = 0; kc < 4; kc++) {
        short8 v;
        #pragma unroll
        for (int j = 0; j < 8; j++)
          v[j] = (short)f2bf(Whh1[g * 128 + kc * 32 + q * 8 + j]);
        wreg[ty][kc] = v;
      }
    }
  } else {
    #pragma unroll
    for (int ty = 0; ty < 4; ty++) {
      const int g2 = ty * 64 + w2 * 16 + c;
      br[ty] = bih2[g2] + bhh2[g2];
      #pragma unroll
      for (int kc = 0; kc < 2; kc++) {
        short8 v;
        #pragma unroll
        for (int j = 0; j < 8; j++)
          v[j] = (short)f2bf(Whh2[g2 * 64 + kc * 32 + q * 8 + j]);
        wreg[ty][kc] = v;
      }
      wreg[ty][2] = (short8){0,0,0,0,0,0,0,0};
      wreg[ty][3] = (short8){0,0,0,0,0,0,0,0};
    }
  }
  const float bdr = (wv == 8 || wv == 9) ? bd[(wv - 8) * 16 + c] : 0.f;
  const float bfr = (wv == 8 && c < 2) ? (bfv[c] + ob[c]) : 0.f;

  f32x4 cst = (f32x4){0,0,0,0};      // c1 (L1 waves) or c2 (L2 waves)
  __syncthreads();

  for (int t = 0; t <= 220; t++) {
    u16* Xc    = X1[t & 1];        // h1(t-1)
    u16* Xn    = X1[(t + 1) & 1];  // h1(t) dest
    u16* Hprev = H2B[t & 1];       // h2(t-2)
    u16* Hdst  = H2B[(t + 1) & 1]; // h2(t-1) dest
    const bool dec  = (t >= 201);
    const bool doL1 = isL1 && (t <= 219);
    const bool doL2 = !isL1 && (t >= 1);

    // ---- L2 waves: chunk loader, 1x per 8 steps (opposite ring slot) ----
    if (!isL1 && (t & 7) == 0) {
      const int cm = (t >> 3) + 1;
      if (cm <= 27) {
        u16* dst = XCH[cm & 1];
        const int t0 = cm << 3;
        if (cm <= 24) {                    // pure-encoder chunk: coalesced float4
          const int i0 = tid - 512;
          #pragma unroll
          for (int p = 0; p < 2; p++) {
            const int idx = i0 + p * 256;
            const int r = idx >> 5, rem = idx & 31, st = rem >> 2, hf = rem & 3;
            const float4v v = *(const float4v*)&xh[(bb + r) * 3200 + (t0 + st) * 16 + hf * 4];
            u16* d = &dst[r * XCS + st * 40 + hf * 4];
            d[0] = f2bf(v[0]); d[1] = f2bf(v[1]); d[2] = f2bf(v[2]); d[3] = f2bf(v[3]);
          }
        } else {                           // decoder chunks 25-27: xfr feats 0..13
          for (int e = tid - 512; e < 16 * 8 * 14; e += 256) {
            const int r = e / 112, rem2 = e % 112, st = rem2 / 14, f = rem2 % 14;
            const int s8 = t0 + st;
            if (s8 < 220)
              dst[r * XCS + st * 40 + f] = f2bf(xfr[(bb + r) * 280 + (s8 - 200) * 14 + f]);
          }
          if (cm == 25) {                  // s=0 feats 14,15 from x_history[..,199,..]
            const int e = tid - 512;
            if (e < 32) {
              const int r = e >> 1, f = 14 + (e & 1);
              dst[r * XCS + f] = f2bf(xh[(bb + r) * 3200 + 199 * 16 + f]);
            }
          }
        }
      }
    }

    // ---- L2 waves: L2 for step t-1 ----
    if (doL2) {
      f32x4 acc2[4];
      #pragma unroll
      for (int ty = 0; ty < 4; ty++)
        acc2[ty] = (f32x4){br[ty], br[ty], br[ty], br[ty]};
      #pragma unroll
      for (int kc = 0; kc < 4; kc++) {
        const short8 fhi = *(const short8*)&Xc[c * X1S + kc * 32 + q * 8];
        #pragma unroll
        for (int ty = 0; ty < 4; ty++) {
          const short8 wf_ = *(const short8*)&W2F[(w2 * 16 + ty * 4 + kc) * 512 + l * 8];
          acc2[ty] = mfma_(fhi, wf_, acc2[ty]);
        }
      }
      #pragma unroll
      for (int kc = 0; kc < 2; kc++) {
        const short8 hhi = *(const short8*)&Hprev[c * H2S + kc * 32 + q * 8];
        #pragma unroll
        for (int ty = 0; ty < 4; ty++)
          acc2[ty] = mfma_(hhi, wreg[ty][kc], acc2[ty]);
      }
      const int u = w2 * 16 + c;
      #pragma unroll
      for (int r = 0; r < 4; r++) {
        float ig = sigm(acc2[0][r]);
        float fg = sigm(acc2[1][r]);
        float gg = tanh_(acc2[2][r]);
        float og = sigm(acc2[3][r]);
        float cn = fg * cst[r] + ig * gg;
        float hn = og * tanh_(cn);
        cst[r] = cn;
        Hdst[(q * 4 + r) * H2S + u] = f2bf(hn);
      }
    }

    // ---- decoder head ----
    if (dec) {
      __syncthreads();                 // #1: h2(t-1) visible
      if (wv == 8 || wv == 9) {
        const int ww = wv - 8;
        f32x4 accd = (f32x4){bdr, bdr, bdr, bdr};
        #pragma unroll
        for (int kc = 0; kc < 2; kc++) {
          const short8 ad  = *(const short8*)&Hdst[c * H2S + kc * 32 + q * 8];
          const short8 wdk = *(const short8*)&WdF[(ww * 2 + kc) * 512 + l * 8];
          accd = mfma_(ad, wdk, accd);
        }
        #pragma unroll
        for (int r = 0; r < 4; r++)
          DB[(q * 4 + r) * DBS + ww * 16 + c] = f2bf(fmaxf(accd[r], 0.f));
      }
      __syncthreads();                 // #2: d visible
      if (wv == 8) {
        const short8 ap  = *(const short8*)&DB[c * DBS + q * 8];
        const short8 wfv = *(const short8*)&WfF[l * 8];
        f32x4 accp = (f32x4){bfr, bfr, bfr, bfr};
        accp = mfma_(ap, wfv, accp);
        if (c < 2) {
          u16* slot = &XCH[(t >> 3) & 1][0];
          #pragma unroll
          for (int r = 0; r < 4; r++) {
            const int b = q * 4 + r;
            out[(bb + b) * 40 + (t - 201) * 2 + c] = accp[r];
            slot[b * XCS + (t & 7) * 40 + 14 + c] = f2bf(accp[r]);  // pred -> x(t)
          }
        }
      }
      __syncthreads();                 // #3: pred in XCH visible
    }

    // ---- L1 waves: L1(t) (x path identical for enc/dec) ----
    if (doL1) {
      f32x4 acc1[4];
      #pragma unroll
      for (int ty = 0; ty < 4; ty++)
        acc1[ty] = (f32x4){br[ty], br[ty], br[ty], br[ty]};
      #pragma unroll
      for (int kc = 0; kc < 4; kc++) {
        const short8 ahi = *(const short8*)&Xc[c * X1S + kc * 32 + q * 8];
        #pragma unroll
        for (int ty = 0; ty < 4; ty++)
          acc1[ty] = mfma_(ahi, wreg[ty][kc], acc1[ty]);
      }
      {
        const short8 ax =
            *(const short8*)&XCH[(t >> 3) & 1][c * XCS + (t & 7) * 40 + q * 8];
        #pragma unroll
        for (int ty = 0; ty < 4; ty++) {
          const short8 wxv = *(const short8*)&W1xF[(ty * 8 + wv) * 512 + l * 8];
          acc1[ty] = mfma_(ax, wxv, acc1[ty]);
        }
      }
      const int u = wv * 16 + c;
      #pragma unroll
      for (int r = 0; r < 4; r++) {
        float ig = sigm(acc1[0][r]);
        float fg = sigm(acc1[1][r]);
        float gg = tanh_(acc1[2][r]);
        float og = sigm(acc1[3][r]);
        float cn = fg * cst[r] + ig * gg;
        float hn = og * tanh_(cn);
        cst[r] = cn;
        Xn[(q * 4 + r) * X1S + u] = f2bf(hn);
      }
    }
    __syncthreads();                   // end: h1(t), h2(t-1), chunk data published
  }
}

extern "C" void kernel_launch(void* const* d_in, const int* in_sizes, int n_in,
                              void* d_out, int out_size, void* d_ws, size_t ws_size,
                              hipStream_t stream) {
  (void)in_sizes; (void)n_in; (void)out_size; (void)d_ws; (void)ws_size;
  spc_lstm<<<dim3(256), dim3(768), 0, stream>>>(
      (const float*)d_in[0],  (const float*)d_in[1],
      (const float*)d_in[2],  (const float*)d_in[3],
      (const float*)d_in[4],  (const float*)d_in[5],
      (const float*)d_in[6],  (const float*)d_in[7],
      (const float*)d_in[8],  (const float*)d_in[9],
      (const float*)d_in[10], (const float*)d_in[11],
      (const float*)d_in[12], (const float*)d_in[13],
      (const float*)d_in[14], (float*)d_out);
}